// Round 1
// baseline (6365.783 us; speedup 1.0000x reference)
//
#include <hip/hip_runtime.h>

#define N 8192
#define MAX_ITER 128
#define EPS 1e-6f

// ---------------------------------------------------------------------------
// init: copy x0 into workspace, zero energy accumulators + done flag
// ---------------------------------------------------------------------------
__global__ __launch_bounds__(256) void init_kernel(const float* __restrict__ x0,
                                                   float* __restrict__ xw,
                                                   float* __restrict__ eacc,
                                                   int* __restrict__ done) {
    int i = blockIdx.x * 256 + threadIdx.x;
    if (i < N) xw[i] = x0[i];
    if (i < MAX_ITER + 1) eacc[i] = 0.0f;
    if (i == 0) *done = 0;
}

// ---------------------------------------------------------------------------
// matvec + fused energy terms:
//   y = W @ x ;  eacc_t += sum_r ( -0.5*x[r]*y[r] - b[r]*x[r] )
// 1024 blocks x 512 threads; 8 waves/block, 1 row/wave; x staged in LDS.
// ---------------------------------------------------------------------------
__global__ __launch_bounds__(512, 4) void mv_kernel(const float* __restrict__ W,
                                                    const float* __restrict__ xw,
                                                    const float* __restrict__ bias,
                                                    float* __restrict__ y,
                                                    float* __restrict__ eacc_t,
                                                    const int* __restrict__ done) {
    if (*done) return;  // uniform: all threads take same path (safe w.r.t. barriers)

    __shared__ float xs[N];      // 32 KB
    __shared__ float wsum[8];

    // stage x -> LDS (512 threads x 16 floats = 4 float4 each)
    {
        const float4* x4 = (const float4*)xw;
        float4* s4 = (float4*)xs;
        for (int i = threadIdx.x; i < N / 4; i += 512) s4[i] = x4[i];
    }
    __syncthreads();

    const int wave = threadIdx.x >> 6;
    const int lane = threadIdx.x & 63;
    const int row  = (blockIdx.x << 3) + wave;

    const float4* Wr  = (const float4*)(W + (size_t)row * N);
    const float4* xs4 = (const float4*)xs;

    float a0 = 0.f, a1 = 0.f, a2 = 0.f, a3 = 0.f;
    // 2048 float4 per row / 64 lanes = 32 passes; 4-wide batches keep 8 loads in flight
    #pragma unroll
    for (int p = 0; p < 8; ++p) {
        int j = p * 256 + lane;
        float4 w0 = Wr[j];         float4 q0 = xs4[j];
        float4 w1 = Wr[j + 64];    float4 q1 = xs4[j + 64];
        float4 w2 = Wr[j + 128];   float4 q2 = xs4[j + 128];
        float4 w3 = Wr[j + 192];   float4 q3 = xs4[j + 192];
        a0 += w0.x * q0.x + w0.y * q0.y + w0.z * q0.z + w0.w * q0.w;
        a1 += w1.x * q1.x + w1.y * q1.y + w1.z * q1.z + w1.w * q1.w;
        a2 += w2.x * q2.x + w2.y * q2.y + w2.z * q2.z + w2.w * q2.w;
        a3 += w3.x * q3.x + w3.y * q3.y + w3.z * q3.z + w3.w * q3.w;
    }
    float tot = (a0 + a1) + (a2 + a3);
    #pragma unroll
    for (int off = 32; off > 0; off >>= 1) tot += __shfl_down(tot, off);

    if (lane == 0) {
        y[row] = tot;
        float xr = xs[row];
        wsum[wave] = -0.5f * xr * tot - bias[row] * xr;
    }
    __syncthreads();
    if (threadIdx.x == 0) {
        float s = 0.f;
        #pragma unroll
        for (int w = 0; w < 8; ++w) s += wsum[w];
        atomicAdd(eacc_t, s);
    }
}

// ---------------------------------------------------------------------------
// update: convergence check on previous two energies, then x = sign(y + b)
// ---------------------------------------------------------------------------
__global__ __launch_bounds__(256) void upd_kernel(const float* __restrict__ y,
                                                  const float* __restrict__ bias,
                                                  float* __restrict__ xw,
                                                  const float* __restrict__ eacc,
                                                  int t,
                                                  int* __restrict__ done) {
    if (*done) return;
    if (t >= 2) {
        // |e_{t-1} - e_{t-2}| < eps  => reference stopped with x_{t-1}; skip update
        float d = fabsf(eacc[t - 1] - eacc[t - 2]);
        if (d < EPS) {
            if (threadIdx.x == 0) *done = 1;  // benign multi-block race, idempotent
            return;
        }
    }
    int i = blockIdx.x * 256 + threadIdx.x;
    float v = y[i] + bias[i];
    xw[i] = (v > 0.f) ? 1.f : ((v < 0.f) ? -1.f : 0.f);
}

// ---------------------------------------------------------------------------
// final copy to d_out
// ---------------------------------------------------------------------------
__global__ __launch_bounds__(256) void out_kernel(const float* __restrict__ xw,
                                                  float* __restrict__ out) {
    int i = blockIdx.x * 256 + threadIdx.x;
    out[i] = xw[i];
}

extern "C" void kernel_launch(void* const* d_in, const int* in_sizes, int n_in,
                              void* d_out, int out_size, void* d_ws, size_t ws_size,
                              hipStream_t stream) {
    const float* x0 = (const float*)d_in[0];   // (8192,)
    const float* W  = (const float*)d_in[1];   // (8192, 8192)
    const float* b  = (const float*)d_in[2];   // (8192,)
    float* out = (float*)d_out;

    // workspace layout (floats)
    float* xw   = (float*)d_ws;          // [N]     current state
    float* y    = xw + N;                // [N]     W @ x
    float* eacc = y + N;                 // [129]   per-iteration energy
    int*   done = (int*)(eacc + MAX_ITER + 2);

    init_kernel<<<N / 256, 256, 0, stream>>>(x0, xw, eacc, done);

    // matvec #0: y = W @ x0, e0 into eacc[0]
    mv_kernel<<<N / 8, 512, 0, stream>>>(W, xw, b, y, eacc + 0, done);

    for (int t = 1; t <= MAX_ITER; ++t) {
        upd_kernel<<<N / 256, 256, 0, stream>>>(y, b, xw, eacc, t, done);
        mv_kernel<<<N / 8, 512, 0, stream>>>(W, xw, b, y, eacc + t, done);
    }

    out_kernel<<<N / 256, 256, 0, stream>>>(xw, out);
}

// Round 2
// 6153.607 us; speedup vs baseline: 1.0345x; 1.0345x over previous
//
#include <hip/hip_runtime.h>

#define N 8192
#define MAX_ITER 128
#define EPS 1e-6f
#define NBLK (N / 8)   // 1024 blocks, 8 rows (waves) per block

// ---------------------------------------------------------------------------
// init: xw = x0 ; eacc[0..128] = 0 ; done = 0
// ---------------------------------------------------------------------------
__global__ __launch_bounds__(256) void init_kernel(const float* __restrict__ x0,
                                                   float* __restrict__ xw,
                                                   float* __restrict__ eacc,
                                                   int* __restrict__ done) {
    int i = blockIdx.x * 256 + threadIdx.x;
    if (i < N) xw[i] = x0[i];
    if (i < MAX_ITER + 1) eacc[i] = 0.0f;
    if (i == 0) *done = 0;
}

__device__ __forceinline__ float signf(float v) {
    return (v > 0.f) ? 1.f : ((v < 0.f) ? -1.f : 0.f);
}

// ---------------------------------------------------------------------------
// fused step t:
//   t==0 : x = x0 (from xw)
//   t>=1 : convergence check on eacc[t-1],eacc[t-2]; if not done,
//          x = sign(yin + b) computed in-block into LDS, slice written to xw
//   then : yout = W @ x ; eacc[t] += -0.5*x·yout - b·x   (block partials)
// Row order reversed on odd t so the L3-freshest tail of the previous pass
// is read first (W = 256 MiB = exact Infinity-Cache fit).
// ---------------------------------------------------------------------------
__global__ __launch_bounds__(512, 4) void mv_kernel(const float* __restrict__ W,
                                                    const float* __restrict__ bias,
                                                    float* __restrict__ xw,
                                                    const float* __restrict__ yin,
                                                    float* __restrict__ yout,
                                                    float* __restrict__ eacc,
                                                    int t,
                                                    int* __restrict__ done) {
    if (*done) return;  // uniform per-kernel: safe w.r.t. barriers
    if (t >= 2) {
        float d = fabsf(eacc[t - 1] - eacc[t - 2]);
        if (d < EPS) {
            if (threadIdx.x == 0) *done = 1;  // idempotent multi-block race
            return;
        }
    }

    __shared__ float xs[N];      // 32 KB
    __shared__ float wsum[8];

    const int bb = (t & 1) ? (NBLK - 1 - (int)blockIdx.x) : (int)blockIdx.x;
    const int rowBase = bb << 3;

    // ---- stage x into LDS ----
    if (t == 0) {
        const float4* x4 = (const float4*)xw;
        float4* s4 = (float4*)xs;
        for (int i = threadIdx.x; i < N / 4; i += 512) s4[i] = x4[i];
    } else {
        const float4* y4 = (const float4*)yin;
        const float4* b4 = (const float4*)bias;
        float4* s4 = (float4*)xs;
        for (int i = threadIdx.x; i < N / 4; i += 512) {
            float4 v = y4[i];
            float4 b = b4[i];
            float4 r;
            r.x = signf(v.x + b.x);
            r.y = signf(v.y + b.y);
            r.z = signf(v.z + b.z);
            r.w = signf(v.w + b.w);
            s4[i] = r;
        }
    }
    __syncthreads();

    // persist this block's slice of the official state (frozen on convergence)
    if (t >= 1 && threadIdx.x < 8) xw[rowBase + threadIdx.x] = xs[rowBase + threadIdx.x];

    // ---- matvec: 1 row per wave ----
    const int wave = threadIdx.x >> 6;
    const int lane = threadIdx.x & 63;
    const int row  = rowBase + wave;

    const float4* Wr  = (const float4*)(W + (size_t)row * N);
    const float4* xs4 = (const float4*)xs;

    float a0 = 0.f, a1 = 0.f, a2 = 0.f, a3 = 0.f;
    #pragma unroll
    for (int p = 0; p < 8; ++p) {
        int j = p * 256 + lane;
        float4 w0 = Wr[j];         float4 q0 = xs4[j];
        float4 w1 = Wr[j + 64];    float4 q1 = xs4[j + 64];
        float4 w2 = Wr[j + 128];   float4 q2 = xs4[j + 128];
        float4 w3 = Wr[j + 192];   float4 q3 = xs4[j + 192];
        a0 += w0.x * q0.x + w0.y * q0.y + w0.z * q0.z + w0.w * q0.w;
        a1 += w1.x * q1.x + w1.y * q1.y + w1.z * q1.z + w1.w * q1.w;
        a2 += w2.x * q2.x + w2.y * q2.y + w2.z * q2.z + w2.w * q2.w;
        a3 += w3.x * q3.x + w3.y * q3.y + w3.z * q3.z + w3.w * q3.w;
    }
    float tot = (a0 + a1) + (a2 + a3);
    #pragma unroll
    for (int off = 32; off > 0; off >>= 1) tot += __shfl_down(tot, off);

    if (lane == 0) {
        yout[row] = tot;
        float xr = xs[row];
        wsum[wave] = -0.5f * xr * tot - bias[row] * xr;
    }
    __syncthreads();
    if (threadIdx.x == 0) {
        float s = 0.f;
        #pragma unroll
        for (int w = 0; w < 8; ++w) s += wsum[w];
        atomicAdd(&eacc[t], s);
    }
}

// ---------------------------------------------------------------------------
// final copy to d_out
// ---------------------------------------------------------------------------
__global__ __launch_bounds__(256) void out_kernel(const float* __restrict__ xw,
                                                  float* __restrict__ out) {
    int i = blockIdx.x * 256 + threadIdx.x;
    out[i] = xw[i];
}

extern "C" void kernel_launch(void* const* d_in, const int* in_sizes, int n_in,
                              void* d_out, int out_size, void* d_ws, size_t ws_size,
                              hipStream_t stream) {
    const float* x0 = (const float*)d_in[0];   // (8192,)
    const float* W  = (const float*)d_in[1];   // (8192, 8192)
    const float* b  = (const float*)d_in[2];   // (8192,)
    float* out = (float*)d_out;

    // workspace layout (floats)
    float* xw   = (float*)d_ws;          // [N]   official (frozen) state
    float* ya   = xw + N;                // [N]   y ping
    float* yb   = ya + N;                // [N]   y pong
    float* eacc = yb + N;                // [129] per-iteration energy
    int*   done = (int*)(eacc + MAX_ITER + 2);

    init_kernel<<<N / 256, 256, 0, stream>>>(x0, xw, eacc, done);

    for (int t = 0; t <= MAX_ITER; ++t) {
        const float* yin = (t & 1) ? ya : yb;   // t=0: unused (stages from xw)
        float*       yout = (t & 1) ? yb : ya;
        mv_kernel<<<NBLK, 512, 0, stream>>>(W, b, xw, yin, yout, eacc, t, done);
    }

    out_kernel<<<N / 256, 256, 0, stream>>>(xw, out);
}

// Round 3
// 5997.782 us; speedup vs baseline: 1.0614x; 1.0260x over previous
//
#include <hip/hip_runtime.h>

#define N 8192
#define MAX_ITER 128
#define EPS 1e-6f
#define NBLK (N / 8)   // 1024 blocks, 8 rows (waves) per block

// ---------------------------------------------------------------------------
// init: zero energy accumulators + done flag (d_ws is poisoned 0xAA each call)
// ---------------------------------------------------------------------------
__global__ __launch_bounds__(256) void init_kernel(float* __restrict__ eacc,
                                                   int* __restrict__ done) {
    int i = threadIdx.x;
    if (i <= MAX_ITER) eacc[i] = 0.0f;
    if (i == 0) *done = 0;
}

// ---------------------------------------------------------------------------
// fused step t (t = 0..128):
//   entry : if done, no-op. If t>=2 and |E[t-1]-E[t-2]| < eps -> done,
//           final state = x_{t-1} which lives in pack[(t-1)&1] (untouched).
//   stage : t==0 -> LDS x := x0 (fp32);  t>=1 -> LDS x := decode(pack[t&1])
//   mv    : tot = W[row,:] @ x  (1 row/wave, float4, 32KB contiguous/wave)
//   emit  : pack[(t+1)&1][row] = sign(tot + b[row])  (int8, speculative)
//           eacc[t] += -0.5*x[row]*tot - b[row]*x[row]  (block partials)
// ---------------------------------------------------------------------------
__global__ __launch_bounds__(512, 4) void mv_kernel(const float* __restrict__ W,
                                                    const float* __restrict__ bias,
                                                    const float* __restrict__ x0,
                                                    const signed char* __restrict__ xin,
                                                    signed char* __restrict__ xnext,
                                                    float* __restrict__ eacc,
                                                    int t,
                                                    int* __restrict__ done) {
    if (t >= 2) {
        if (*done) return;  // uniform: safe w.r.t. barriers
        float d = fabsf(eacc[t - 1] - eacc[t - 2]);
        if (d < EPS) {
            // reference's final x = x_{t-1}, stored in pack[(t-1)&1]
            if (threadIdx.x == 0) *done = 1 + ((t - 1) & 1);  // idempotent race
            return;
        }
    }

    __shared__ float xs[N];      // 32 KB
    __shared__ float wsum[8];

    // ---- stage x into LDS ----
    if (t == 0) {
        const float4* x4 = (const float4*)x0;
        float4* s4 = (float4*)xs;
        for (int i = threadIdx.x; i < N / 4; i += 512) s4[i] = x4[i];
    } else {
        // 16 coalesced byte loads / thread, conflict-free scalar LDS writes
        #pragma unroll
        for (int k = 0; k < 16; ++k) {
            int e = threadIdx.x + k * 512;
            xs[e] = (float)xin[e];
        }
    }
    __syncthreads();

    // ---- matvec: 1 row per wave ----
    const int wave = threadIdx.x >> 6;
    const int lane = threadIdx.x & 63;
    const int row  = ((int)blockIdx.x << 3) + wave;

    const float4* Wr  = (const float4*)(W + (size_t)row * N);
    const float4* xs4 = (const float4*)xs;

    float a0 = 0.f, a1 = 0.f, a2 = 0.f, a3 = 0.f;
    #pragma unroll
    for (int p = 0; p < 8; ++p) {
        int j = p * 256 + lane;
        float4 w0 = Wr[j];         float4 q0 = xs4[j];
        float4 w1 = Wr[j + 64];    float4 q1 = xs4[j + 64];
        float4 w2 = Wr[j + 128];   float4 q2 = xs4[j + 128];
        float4 w3 = Wr[j + 192];   float4 q3 = xs4[j + 192];
        a0 += w0.x * q0.x + w0.y * q0.y + w0.z * q0.z + w0.w * q0.w;
        a1 += w1.x * q1.x + w1.y * q1.y + w1.z * q1.z + w1.w * q1.w;
        a2 += w2.x * q2.x + w2.y * q2.y + w2.z * q2.z + w2.w * q2.w;
        a3 += w3.x * q3.x + w3.y * q3.y + w3.z * q3.z + w3.w * q3.w;
    }
    float tot = (a0 + a1) + (a2 + a3);
    #pragma unroll
    for (int off = 32; off > 0; off >>= 1) tot += __shfl_down(tot, off);

    if (lane == 0) {
        float br = bias[row];
        float v = tot + br;
        xnext[row] = (signed char)((v > 0.f) ? 1 : ((v < 0.f) ? -1 : 0));
        float xr = xs[row];
        wsum[wave] = -0.5f * xr * tot - br * xr;
    }
    __syncthreads();
    if (threadIdx.x == 0) {
        float s = 0.f;
        #pragma unroll
        for (int w = 0; w < 8; ++w) s += wsum[w];
        atomicAdd(&eacc[t], s);
    }
}

// ---------------------------------------------------------------------------
// final: decode the winning packed buffer to fp32 out
// ---------------------------------------------------------------------------
__global__ __launch_bounds__(256) void out_kernel(const signed char* __restrict__ p0,
                                                  const signed char* __restrict__ p1,
                                                  const int* __restrict__ done,
                                                  float* __restrict__ out) {
    int i = blockIdx.x * 256 + threadIdx.x;
    int d = *done;
    // no convergence: final = x_128, staged by kernel 128 from pack[128&1]=pack[0]
    const signed char* p = d ? ((d - 1) ? p1 : p0) : p0;
    out[i] = (float)p[i];
}

extern "C" void kernel_launch(void* const* d_in, const int* in_sizes, int n_in,
                              void* d_out, int out_size, void* d_ws, size_t ws_size,
                              hipStream_t stream) {
    const float* x0 = (const float*)d_in[0];   // (8192,)
    const float* W  = (const float*)d_in[1];   // (8192, 8192)
    const float* b  = (const float*)d_in[2];   // (8192,)
    float* out = (float*)d_out;

    // workspace layout
    float*       eacc = (float*)d_ws;                 // [129] energies
    int*         done = (int*)(eacc + MAX_ITER + 2);  // flag (0 or 1+bufidx)
    signed char* p0   = (signed char*)(done + 16);    // [N] packed state ping
    signed char* p1   = p0 + N;                       // [N] packed state pong

    init_kernel<<<1, 256, 0, stream>>>(eacc, done);

    for (int t = 0; t <= MAX_ITER; ++t) {
        // kernel t reads pack[t&1] (unused at t=0), writes pack[(t+1)&1]
        const signed char* xin   = (t & 1) ? p1 : p0;
        signed char*       xnext = (t & 1) ? p0 : p1;
        mv_kernel<<<NBLK, 512, 0, stream>>>(W, b, x0, xin, xnext, eacc, t, done);
    }

    out_kernel<<<N / 256, 256, 0, stream>>>(p0, p1, done, out);
}